// Round 14
// baseline (403.727 us; speedup 1.0000x reference)
//
#include <hip/hip_runtime.h>
#include <hip/hip_bf16.h>
#include <math.h>

#define HDIM 100
#define NFACT 262144
#define FPB   128             // facts per tile (8 waves x 16)
#define NBLK_T 2048           // tiles
#define TPB   4               // tiles per persistent block
#define GRID  512             // 2 blocks/CU x 256 CU — whole grid co-resident
#define NTHREADS 512

// K packed to 224: k in [0,112) -> (f - oc) (valid k<100), k in [112,224) -> (f - m)
// (valid k-112<100). Dead k ranges have W1-frag == 0 and z == 0. 112 % 8 == 0 so no
// 8-element MFMA k-group straddles the boundary.
#define KHALF 112
#define NJT 7                 // j-tiles of 16 (112 >= 100)
#define NKC 7                 // k-chunks of 32 (224)
#define NBFRAG (NJT * NKC * 64)   // 3136 uint4 = 50176 B

#define NCOPY 116             // accumulator stripe: corr[112] + S at [112]
#define NSTRIPE 4

using short8 = __attribute__((ext_vector_type(8))) short;
using f32x4  = __attribute__((ext_vector_type(4))) float;

// ---------------- ws float-offset layout ----------------
#define WS_B    0                 // 12544 floats (3136 uint4 W1-fragments, bf16 bits)
#define WS_ACC  12544             // NSTRIPE stripes x 116 floats (zeroed by k_prep_b)

__device__ __forceinline__ unsigned short f2bf(float x) {
    unsigned u = __builtin_bit_cast(unsigned, x);
    u += 0x7FFFu + ((u >> 16) & 1u);          // RNE round to bf16
    return (unsigned short)(u >> 16);
}

__device__ __forceinline__ float tanh_fast(float x) {
    float e = __expf(2.0f * x);
    return 1.0f - 2.0f / (1.0f + e);
}

// ---- Precompute W1 fragments (bf16), order [jt][kc][lane][8]; zero accumulators ----
// MFMA A operand: A[row=j][k]; per lane: j = jt*16 + (lane&15), k = kc*32 + (lane>>4)*8 + e.
__global__ __launch_bounds__(256) void k_prep_b(const float* __restrict__ W1,
                                                float* __restrict__ ws) {
    int tg = blockIdx.x * 256 + threadIdx.x;
    if (tg < NSTRIPE * NCOPY) ws[WS_ACC + tg] = 0.f;   // zero all stripes each call
    if (tg >= NBFRAG) return;
    int lane = tg & 63;
    int kc = (tg >> 6) % NKC;
    int jt = tg / (NKC * 64);
    int g = lane >> 4, r = lane & 15;
    int j = jt * 16 + r;
    unsigned short v[8];
    #pragma unroll
    for (int e = 0; e < 8; e++) {
        int kglob = kc * 32 + g * 8 + e;
        int half = (kglob >= KHALF) ? 1 : 0;
        int koff = kglob - half * KHALF;
        float x = 0.f;
        if (j < HDIM && koff < HDIM) x = W1[j * 200 + half * HDIM + koff];
        v[e] = f2bf(x);
    }
    uint4 d;
    d.x = (unsigned)v[0] | ((unsigned)v[1] << 16);
    d.y = (unsigned)v[2] | ((unsigned)v[3] << 16);
    d.z = (unsigned)v[4] | ((unsigned)v[5] << 16);
    d.w = (unsigned)v[6] | ((unsigned)v[7] << 16);
    ((uint4*)(ws + WS_B))[tg] = d;
}

__device__ __forceinline__ float4 ld4c(const float* p, bool ok) {
    float4 z = make_float4(0.f, 0.f, 0.f, 0.f);
    return ok ? *(const float4*)p : z;
}

__device__ __forceinline__ uint4 pack_diff_u(float4 a0, float4 a1,
                                             float4 b0, float4 b1) {
    union { __hip_bfloat16 h[8]; uint4 u; } u;
    u.h[0] = __float2bfloat16(a0.x - b0.x); u.h[1] = __float2bfloat16(a0.y - b0.y);
    u.h[2] = __float2bfloat16(a0.z - b0.z); u.h[3] = __float2bfloat16(a0.w - b0.w);
    u.h[4] = __float2bfloat16(a1.x - b1.x); u.h[5] = __float2bfloat16(a1.y - b1.y);
    u.h[6] = __float2bfloat16(a1.z - b1.z); u.h[7] = __float2bfloat16(a1.w - b1.w);
    return u.u;
}

// DPP row-rotate add (VALU pipe): x + rotate_within_16(x, N)
template<int CTRL>
__device__ __forceinline__ float dpp_radd(float x) {
    int y = __builtin_amdgcn_update_dpp(0, __builtin_bit_cast(int, x),
                                        CTRL, 0xF, 0xF, true);
    return x + __builtin_bit_cast(float, y);
}
__device__ __forceinline__ float row_reduce16(float x) {
    x = dpp_radd<0x121>(x);   // row_ror:1
    x = dpp_radd<0x122>(x);   // row_ror:2
    x = dpp_radd<0x124>(x);   // row_ror:4
    x = dpp_radd<0x128>(x);   // row_ror:8
    return x;                 // all 16 lanes of the row hold the row-sum
}

// PERSISTENT: 512 blocks (whole grid resident). Stage W1/params ONCE, then loop
// 4 tiles with NO barriers inside the loop: pooling partials accumulate in regs,
// softmax denom in a reg (no max-shift needed: |logit| <= sum|W2| ~ 8). One DPP
// reduce + LDS exchange + flush per BLOCK. min-wave=4 (6/8 cap VGPR -> spill, R10/R11).
__global__ __launch_bounds__(NTHREADS, 4) void k_logits(
        const float* __restrict__ fe,
        const float* __restrict__ oc,
        const float* __restrict__ mvec,
        const float* __restrict__ b1,
        const float* __restrict__ W2,
        float* __restrict__ ws) {
    __shared__ __align__(16) uint4 Bs[NBFRAG];         // 50176 B (W1 table, persistent)
    __shared__ float pool2[8 * KHALF];                 // 3584 B
    __shared__ float cpad[2 * KHALF];                  // oc | m, zero-padded
    __shared__ float bw[2 * KHALF];                    // b1 | W2, zero-padded
    __shared__ float sS;

    int t = threadIdx.x;
    int w = t >> 6, lane = t & 63, g = lane >> 4, r = lane & 15;

    if (t == 0) sS = 0.f;

    // ---- stage zero-padded params to LDS (one-time, coalesced) ----
    if (t < 2 * KHALF) {
        int half = t / KHALF, k = t % KHALF;
        cpad[t] = (k < HDIM) ? (half ? mvec[k] : oc[k]) : 0.f;
        bw[t]   = (k < HDIM) ? (half ? W2[k]   : b1[k]) : 0.f;
    }

    // ---- async stage W1 table: global -> LDS, width 16, linear (ONCE per block) ----
    {
        const uint4* Bg = (const uint4*)(ws + WS_B);
        #pragma unroll
        for (int i = 0; i < 7; i++) {
            int base = i * 512 + w * 64;          // wave-uniform
            if (base < NBFRAG) {
                __builtin_amdgcn_global_load_lds(
                    (const __attribute__((address_space(1))) unsigned int*)(Bg + base + lane),
                    (__attribute__((address_space(3))) unsigned int*)(Bs + base),
                    16, 0, 0);
            }
        }
    }
    __syncthreads();   // drains vmcnt -> Bs/cpad/bw ready

    // ---- persistent accumulators (regs) ----
    float p[4][8];
    #pragma unroll
    for (int c = 0; c < 4; c++)
        #pragma unroll
        for (int e = 0; e < 8; e++) p[c][e] = 0.f;
    float sacc = 0.f;

    // ---- barrier-free tile loop ----
    for (int tt = 0; tt < TPB; tt++) {
        int tile = blockIdx.x * TPB + tt;
        long n0 = (long)tile * FPB;
        const float* fp = fe + (n0 + w * 16 + r) * HDIM;

        // per-lane f loads (unconditional except the very last tile)
        float4 f0c[NKC], f1c[NKC];
        if (tile != NBLK_T - 1) {
            #pragma unroll
            for (int kc = 0; kc < NKC; kc++) {
                int pk = kc * 32 + g * 8;
                int col = (pk >= KHALF) ? (pk - KHALF) : pk;
                f0c[kc] = *(const float4*)(fp + col);      // may read into next row:
                f1c[kc] = *(const float4*)(fp + col + 4);  // finite; killed by W1=0
            }
        } else {
            #pragma unroll
            for (int kc = 0; kc < NKC; kc++) {
                int pk = kc * 32 + g * 8;
                int col = (pk >= KHALF) ? (pk - KHALF) : pk;
                f0c[kc] = ld4c(fp + col, col < HDIM);
                f1c[kc] = ld4c(fp + col + 4, col + 4 < HDIM);
            }
        }

        // z build from LDS-padded params (no masks)
        uint4 zabs[NKC];
        uint4 zsig[4];             // signed chunks kc=0..3 (pooling, oc-half)
        #pragma unroll
        for (int kc = 0; kc < NKC; kc++) {
            int pk = kc * 32 + g * 8;
            float4 s0 = *(const float4*)(cpad + pk);
            float4 s1 = *(const float4*)(cpad + pk + 4);
            uint4 u = pack_diff_u(f0c[kc], f1c[kc], s0, s1);
            if (kc < 4) zsig[kc] = u;
            u.x &= 0x7FFF7FFFu; u.y &= 0x7FFF7FFFu;
            u.z &= 0x7FFF7FFFu; u.w &= 0x7FFF7FFFu;
            zabs[kc] = u;
        }

        // GEMM: C[j][fact] = mfma(W1frag, |z|); C col = r = my fact; b1 in C-init
        float gacc = 0.f;
        #pragma unroll
        for (int jt = 0; jt < NJT; jt++) {
            int jb = jt * 16 + g * 4;
            float4 b1q = *(const float4*)(bw + jb);
            float4 w2q = *(const float4*)(bw + KHALF + jb);
            f32x4 acc = {b1q.x, b1q.y, b1q.z, b1q.w};
            #pragma unroll
            for (int kc = 0; kc < NKC; kc++) {
                short8 av = __builtin_bit_cast(short8, Bs[(jt * NKC + kc) * 64 + lane]);
                acc = __builtin_amdgcn_mfma_f32_16x16x32_bf16(
                    av, __builtin_bit_cast(short8, zabs[kc]), acc, 0, 0, 0);
            }
            gacc = fmaf(tanh_fast(acc[0]), w2q.x, gacc);
            gacc = fmaf(tanh_fast(acc[1]), w2q.y, gacc);
            gacc = fmaf(tanh_fast(acc[2]), w2q.z, gacc);
            gacc = fmaf(tanh_fast(acc[3]), w2q.w, gacc);
        }
        gacc += __shfl_xor(gacc, 16);
        gacc += __shfl_xor(gacc, 32);
        float w_r = __expf(gacc);   // b2 dropped (softmax-invariant)

        sacc += w_r;

        // pooling accumulate in regs: p[k] += w_r * (f-oc)[r][k]
        #pragma unroll
        for (int c = 0; c < 4; c++) {
            union { uint4 u; unsigned short us[8]; } uz; uz.u = zsig[c];
            #pragma unroll
            for (int e = 0; e < 8; e++) {
                float zf = __builtin_bit_cast(float, ((unsigned)uz.us[e]) << 16);
                p[c][e] = fmaf(w_r, zf, p[c][e]);
            }
        }
    }

    // ---- end-of-block reduction: DPP over the 16 facts of each row-group ----
    #pragma unroll
    for (int c = 0; c < 4; c++)
        #pragma unroll
        for (int e = 0; e < 8; e++) p[c][e] = row_reduce16(p[c][e]);
    float s16 = row_reduce16(sacc);   // w_r duplicated across g; take one wave-add
    if (lane == 0) atomicAdd(&sS, s16);

    if (r == 0) {      // lanes g=0..3 write their oc-half slots (pk<112)
        #pragma unroll
        for (int c = 0; c < 4; c++) {
            int pk = c * 32 + g * 8;
            if (pk < KHALF) {
                float* dst = pool2 + w * KHALF + pk;
                *(float4*)(dst)     = make_float4(p[c][0], p[c][1], p[c][2], p[c][3]);
                *(float4*)(dst + 4) = make_float4(p[c][4], p[c][5], p[c][6], p[c][7]);
            }
        }
    }
    __syncthreads();

    // ---- block flush -> striped global accumulator ----
    int cp = (blockIdx.x & (NSTRIPE - 1)) * NCOPY;
    if (t < KHALF) {
        float a = 0.f;
        #pragma unroll
        for (int w8 = 0; w8 < 8; w8++) a += pool2[w8 * KHALF + t];
        if (t < HDIM) atomicAdd(&ws[WS_ACC + cp + t], a);
    }
    if (t == 0) atomicAdd(&ws[WS_ACC + cp + KHALF], sS);
}

// Tiny epilogue: c = oc + corr/S; gated update. One block.
__global__ __launch_bounds__(128) void k_final(
        const float* __restrict__ mvec,
        const float* __restrict__ oc,
        const float* __restrict__ W3,
        const float* __restrict__ b3,
        const float* __restrict__ ws,
        float* __restrict__ out) {
    __shared__ float vv[300];
    int t = threadIdx.x;
    float S = 0.f;
    #pragma unroll
    for (int i = 0; i < NSTRIPE; i++) S += ws[WS_ACC + i * NCOPY + KHALF];
    if (t < HDIM) {
        float corr = 0.f;
        #pragma unroll
        for (int i = 0; i < NSTRIPE; i++) corr += ws[WS_ACC + i * NCOPY + t];
        vv[t] = mvec[t];
        vv[HDIM + t] = oc[t] + corr / S;
        vv[2 * HDIM + t] = oc[t];
    }
    __syncthreads();
    if (t < HDIM) {
        float a = b3[t];
        const float* wr = W3 + t * 3 * HDIM;
        #pragma unroll 4
        for (int k = 0; k < 3 * HDIM; k++) a = fmaf(wr[k], vv[k], a);
        out[t] = fmaxf(a, 0.f);
    }
}

extern "C" void kernel_launch(void* const* d_in, const int* in_sizes, int n_in,
                              void* d_out, int out_size, void* d_ws, size_t ws_size,
                              hipStream_t stream) {
    const float* mvec = (const float*)d_in[0];
    const float* oh   = (const float*)d_in[1];
    const float* fe   = (const float*)d_in[2];
    const float* W1   = (const float*)d_in[3];
    const float* b1   = (const float*)d_in[4];
    const float* W2   = (const float*)d_in[5];
    const float* W3   = (const float*)d_in[7];
    const float* b3   = (const float*)d_in[8];
    float* ws  = (float*)d_ws;
    float* out = (float*)d_out;

    k_prep_b<<<15, 256, 0, stream>>>(W1, ws);
    k_logits<<<GRID, NTHREADS, 0, stream>>>(fe, oh, mvec, b1, W2, ws);
    k_final<<<1, 128, 0, stream>>>(mvec, oh, W3, b3, ws, out);
}

// Round 15
// 379.275 us; speedup vs baseline: 1.0645x; 1.0645x over previous
//
#include <hip/hip_runtime.h>
#include <hip/hip_bf16.h>
#include <math.h>

#define HDIM 100
#define NFACT 262144
#define FPB   128             // facts per tile (8 waves x 16)
#define NBLK_T 2048           // tiles total
#define TPB   4               // tiles per persistent-lite block
#define GRID  (NBLK_T / TPB)  // 512 blocks
#define NTHREADS 512

// K packed to 224: k in [0,112) -> (f - oc) (valid k<100), k in [112,224) -> (f - m)
// (valid k-112<100). Dead k ranges have W1-frag == 0 and z == 0. 112 % 8 == 0 so no
// 8-element MFMA k-group straddles the boundary.
#define KHALF 112
#define NJT 7                 // j-tiles of 16 (112 >= 100)
#define NKC 7                 // k-chunks of 32 (224)
#define NBFRAG (NJT * NKC * 64)   // 3136 uint4 = 50176 B

#define NCOPY 116             // accumulator stripe: corr[112] + S at [112]
#define NSTRIPE 4             // 32 stripes thrashed L2 lines (R12: 49 MB writes)

using short8 = __attribute__((ext_vector_type(8))) short;
using f32x4  = __attribute__((ext_vector_type(4))) float;

// ---------------- ws float-offset layout ----------------
#define WS_B    0                 // 12544 floats (3136 uint4 W1-fragments, bf16 bits)
#define WS_ACC  12544             // NSTRIPE stripes x 116 floats (zeroed by k_prep_b)

__device__ __forceinline__ unsigned short f2bf(float x) {
    unsigned u = __builtin_bit_cast(unsigned, x);
    u += 0x7FFFu + ((u >> 16) & 1u);          // RNE round to bf16
    return (unsigned short)(u >> 16);
}

__device__ __forceinline__ float tanh_fast(float x) {
    float e = __expf(2.0f * x);
    return 1.0f - 2.0f / (1.0f + e);
}

// ---- Precompute W1 fragments (bf16), order [jt][kc][lane][8]; zero accumulators ----
// MFMA A operand: A[row=j][k]; per lane: j = jt*16 + (lane&15), k = kc*32 + (lane>>4)*8 + e.
__global__ __launch_bounds__(256) void k_prep_b(const float* __restrict__ W1,
                                                float* __restrict__ ws) {
    int tg = blockIdx.x * 256 + threadIdx.x;
    if (tg < NSTRIPE * NCOPY) ws[WS_ACC + tg] = 0.f;   // zero all stripes each call
    if (tg >= NBFRAG) return;
    int lane = tg & 63;
    int kc = (tg >> 6) % NKC;
    int jt = tg / (NKC * 64);
    int g = lane >> 4, r = lane & 15;
    int j = jt * 16 + r;
    unsigned short v[8];
    #pragma unroll
    for (int e = 0; e < 8; e++) {
        int kglob = kc * 32 + g * 8 + e;
        int half = (kglob >= KHALF) ? 1 : 0;
        int koff = kglob - half * KHALF;
        float x = 0.f;
        if (j < HDIM && koff < HDIM) x = W1[j * 200 + half * HDIM + koff];
        v[e] = f2bf(x);
    }
    uint4 d;
    d.x = (unsigned)v[0] | ((unsigned)v[1] << 16);
    d.y = (unsigned)v[2] | ((unsigned)v[3] << 16);
    d.z = (unsigned)v[4] | ((unsigned)v[5] << 16);
    d.w = (unsigned)v[6] | ((unsigned)v[7] << 16);
    ((uint4*)(ws + WS_B))[tg] = d;
}

__device__ __forceinline__ float4 ld4c(const float* p, bool ok) {
    float4 z = make_float4(0.f, 0.f, 0.f, 0.f);
    return ok ? *(const float4*)p : z;
}

__device__ __forceinline__ uint4 pack_diff_u(float4 a0, float4 a1,
                                             float4 b0, float4 b1) {
    union { __hip_bfloat16 h[8]; uint4 u; } u;
    u.h[0] = __float2bfloat16(a0.x - b0.x); u.h[1] = __float2bfloat16(a0.y - b0.y);
    u.h[2] = __float2bfloat16(a0.z - b0.z); u.h[3] = __float2bfloat16(a0.w - b0.w);
    u.h[4] = __float2bfloat16(a1.x - b1.x); u.h[5] = __float2bfloat16(a1.y - b1.y);
    u.h[6] = __float2bfloat16(a1.z - b1.z); u.h[7] = __float2bfloat16(a1.w - b1.w);
    return u.u;
}

// DPP row-rotate add (VALU pipe): x + rotate_within_16(x, N)
template<int CTRL>
__device__ __forceinline__ float dpp_radd(float x) {
    int y = __builtin_amdgcn_update_dpp(0, __builtin_bit_cast(int, x),
                                        CTRL, 0xF, 0xF, true);
    return x + __builtin_bit_cast(float, y);
}
__device__ __forceinline__ float row_reduce16(float x) {
    x = dpp_radd<0x121>(x);   // row_ror:1
    x = dpp_radd<0x122>(x);   // row_ror:2
    x = dpp_radd<0x124>(x);   // row_ror:4
    x = dpp_radd<0x128>(x);   // row_ror:8
    return x;                 // all 16 lanes of the row hold the row-sum
}

// PERSISTENT-LITE: 512 blocks x 4 tiles. W1/params staged ONCE per block; the
// tile loop carries ONLY sacc (1 reg) — pooling partials are DPP-reduced per
// tile (R13's proven schedule) and accumulated into WAVE-PRIVATE LDS slices
// (no barriers, no atomics inside the loop). min-wave=4 (6/8 spill: R10/R11);
// register-held tile accumulators spill (R14) — do NOT hold p[] across tiles.
__global__ __launch_bounds__(NTHREADS, 4) void k_logits(
        const float* __restrict__ fe,
        const float* __restrict__ oc,
        const float* __restrict__ mvec,
        const float* __restrict__ b1,
        const float* __restrict__ W2,
        float* __restrict__ ws) {
    __shared__ __align__(16) uint4 Bs[NBFRAG];         // 50176 B (W1 table, persistent)
    __shared__ float pool2[8 * KHALF];                 // 3584 B, wave-private slices
    __shared__ float cpad[2 * KHALF];                  // oc | m, zero-padded
    __shared__ float bw[2 * KHALF];                    // b1 | W2, zero-padded
    __shared__ float sS;

    int t = threadIdx.x;
    int w = t >> 6, lane = t & 63, g = lane >> 4, r = lane & 15;

    if (t == 0) sS = 0.f;
    for (int i = t; i < 8 * KHALF; i += NTHREADS) pool2[i] = 0.f;

    // ---- stage zero-padded params to LDS (one-time, coalesced) ----
    if (t < 2 * KHALF) {
        int half = t / KHALF, k = t % KHALF;
        cpad[t] = (k < HDIM) ? (half ? mvec[k] : oc[k]) : 0.f;
        bw[t]   = (k < HDIM) ? (half ? W2[k]   : b1[k]) : 0.f;
    }

    // ---- async stage W1 table: global -> LDS, width 16, linear (ONCE per block) ----
    {
        const uint4* Bg = (const uint4*)(ws + WS_B);
        #pragma unroll
        for (int i = 0; i < 7; i++) {
            int base = i * 512 + w * 64;          // wave-uniform
            if (base < NBFRAG) {
                __builtin_amdgcn_global_load_lds(
                    (const __attribute__((address_space(1))) unsigned int*)(Bg + base + lane),
                    (__attribute__((address_space(3))) unsigned int*)(Bs + base),
                    16, 0, 0);
            }
        }
    }
    __syncthreads();   // drains vmcnt -> Bs/cpad/bw/pool2 ready

    float sacc = 0.f;

    #pragma unroll 1   // keep per-iteration register pressure at R13's level
    for (int tt = 0; tt < TPB; tt++) {
        int tile = blockIdx.x * TPB + tt;
        long n0 = (long)tile * FPB;
        const float* fp = fe + (n0 + w * 16 + r) * HDIM;

        // per-lane f loads (unconditional except the very last tile of the grid)
        float4 f0c[NKC], f1c[NKC];
        if (tile != NBLK_T - 1) {
            #pragma unroll
            for (int kc = 0; kc < NKC; kc++) {
                int pk = kc * 32 + g * 8;
                int col = (pk >= KHALF) ? (pk - KHALF) : pk;
                f0c[kc] = *(const float4*)(fp + col);      // may read into next row:
                f1c[kc] = *(const float4*)(fp + col + 4);  // finite; killed by W1=0
            }
        } else {
            #pragma unroll
            for (int kc = 0; kc < NKC; kc++) {
                int pk = kc * 32 + g * 8;
                int col = (pk >= KHALF) ? (pk - KHALF) : pk;
                f0c[kc] = ld4c(fp + col, col < HDIM);
                f1c[kc] = ld4c(fp + col + 4, col + 4 < HDIM);
            }
        }

        // z build from LDS-padded params (no masks)
        uint4 zabs[NKC];
        uint4 zsig[4];             // signed chunks kc=0..3 (pooling, oc-half)
        #pragma unroll
        for (int kc = 0; kc < NKC; kc++) {
            int pk = kc * 32 + g * 8;
            float4 s0 = *(const float4*)(cpad + pk);
            float4 s1 = *(const float4*)(cpad + pk + 4);
            uint4 u = pack_diff_u(f0c[kc], f1c[kc], s0, s1);
            if (kc < 4) zsig[kc] = u;
            u.x &= 0x7FFF7FFFu; u.y &= 0x7FFF7FFFu;
            u.z &= 0x7FFF7FFFu; u.w &= 0x7FFF7FFFu;
            zabs[kc] = u;
        }

        // GEMM: C[j][fact] = mfma(W1frag, |z|); C col = r = my fact; b1 in C-init
        float gacc = 0.f;
        #pragma unroll
        for (int jt = 0; jt < NJT; jt++) {
            int jb = jt * 16 + g * 4;
            float4 b1q = *(const float4*)(bw + jb);
            float4 w2q = *(const float4*)(bw + KHALF + jb);
            f32x4 acc = {b1q.x, b1q.y, b1q.z, b1q.w};
            #pragma unroll
            for (int kc = 0; kc < NKC; kc++) {
                short8 av = __builtin_bit_cast(short8, Bs[(jt * NKC + kc) * 64 + lane]);
                acc = __builtin_amdgcn_mfma_f32_16x16x32_bf16(
                    av, __builtin_bit_cast(short8, zabs[kc]), acc, 0, 0, 0);
            }
            gacc = fmaf(tanh_fast(acc[0]), w2q.x, gacc);
            gacc = fmaf(tanh_fast(acc[1]), w2q.y, gacc);
            gacc = fmaf(tanh_fast(acc[2]), w2q.z, gacc);
            gacc = fmaf(tanh_fast(acc[3]), w2q.w, gacc);
        }
        gacc += __shfl_xor(gacc, 16);
        gacc += __shfl_xor(gacc, 32);
        float w_r = __expf(gacc);   // b2 dropped (softmax-invariant); |logit| <~ 8

        sacc += w_r;                // only loop-carried register

        // pooling: p[k] = sum_r w_r*(f-oc)[r][k]; DPP-reduce; accumulate into
        // this wave's PRIVATE pool2 slice (same lane each tile -> no race).
        float p[4][8];
        #pragma unroll
        for (int c = 0; c < 4; c++) {
            union { uint4 u; unsigned short us[8]; } uz; uz.u = zsig[c];
            #pragma unroll
            for (int e = 0; e < 8; e++) {
                float zf = __builtin_bit_cast(float, ((unsigned)uz.us[e]) << 16);
                p[c][e] = w_r * zf;
            }
        }
        #pragma unroll
        for (int c = 0; c < 4; c++)
            #pragma unroll
            for (int e = 0; e < 8; e++) p[c][e] = row_reduce16(p[c][e]);

        if (r == 0) {      // lanes g=0..3 own their oc-half slots (pk<112)
            #pragma unroll
            for (int c = 0; c < 4; c++) {
                int pk = c * 32 + g * 8;
                if (pk < KHALF) {
                    float* dst = pool2 + w * KHALF + pk;
                    float4 a0 = *(float4*)(dst);
                    float4 a1 = *(float4*)(dst + 4);
                    a0.x += p[c][0]; a0.y += p[c][1]; a0.z += p[c][2]; a0.w += p[c][3];
                    a1.x += p[c][4]; a1.y += p[c][5]; a1.z += p[c][6]; a1.w += p[c][7];
                    *(float4*)(dst)     = a0;
                    *(float4*)(dst + 4) = a1;
                }
            }
        }
    }

    // ---- end-of-block: denom partial + flush ----
    float s16 = row_reduce16(sacc);   // w_r duplicated across g; take one copy
    if (lane == 0) atomicAdd(&sS, s16);
    __syncthreads();

    int cp = (blockIdx.x & (NSTRIPE - 1)) * NCOPY;
    if (t < KHALF) {
        float a = 0.f;
        #pragma unroll
        for (int w8 = 0; w8 < 8; w8++) a += pool2[w8 * KHALF + t];
        if (t < HDIM) atomicAdd(&ws[WS_ACC + cp + t], a);
    }
    if (t == 0) atomicAdd(&ws[WS_ACC + cp + KHALF], sS);
}

// Tiny epilogue: c = oc + corr/S; gated update. One block.
__global__ __launch_bounds__(128) void k_final(
        const float* __restrict__ mvec,
        const float* __restrict__ oc,
        const float* __restrict__ W3,
        const float* __restrict__ b3,
        const float* __restrict__ ws,
        float* __restrict__ out) {
    __shared__ float vv[300];
    int t = threadIdx.x;
    float S = 0.f;
    #pragma unroll
    for (int i = 0; i < NSTRIPE; i++) S += ws[WS_ACC + i * NCOPY + KHALF];
    if (t < HDIM) {
        float corr = 0.f;
        #pragma unroll
        for (int i = 0; i < NSTRIPE; i++) corr += ws[WS_ACC + i * NCOPY + t];
        vv[t] = mvec[t];
        vv[HDIM + t] = oc[t] + corr / S;
        vv[2 * HDIM + t] = oc[t];
    }
    __syncthreads();
    if (t < HDIM) {
        float a = b3[t];
        const float* wr = W3 + t * 3 * HDIM;
        #pragma unroll 4
        for (int k = 0; k < 3 * HDIM; k++) a = fmaf(wr[k], vv[k], a);
        out[t] = fmaxf(a, 0.f);
    }
}

extern "C" void kernel_launch(void* const* d_in, const int* in_sizes, int n_in,
                              void* d_out, int out_size, void* d_ws, size_t ws_size,
                              hipStream_t stream) {
    const float* mvec = (const float*)d_in[0];
    const float* oh   = (const float*)d_in[1];
    const float* fe   = (const float*)d_in[2];
    const float* W1   = (const float*)d_in[3];
    const float* b1   = (const float*)d_in[4];
    const float* W2   = (const float*)d_in[5];
    const float* W3   = (const float*)d_in[7];
    const float* b3   = (const float*)d_in[8];
    float* ws  = (float*)d_ws;
    float* out = (float*)d_out;

    k_prep_b<<<15, 256, 0, stream>>>(W1, ws);
    k_logits<<<GRID, NTHREADS, 0, stream>>>(fe, oh, mvec, b1, W2, ws);
    k_final<<<1, 128, 0, stream>>>(mvec, oh, W3, b3, ws, out);
}

// Round 16
// 194.993 us; speedup vs baseline: 2.0705x; 1.9451x over previous
//
#include <hip/hip_runtime.h>
#include <hip/hip_bf16.h>
#include <math.h>

#define HDIM 100
#define NFACT 262144
#define FPB   128             // facts per tile (8 waves x 16)
#define NBLK_T 2048           // tiles total
#define TPB   4               // tiles per persistent-lite block
#define GRID  (NBLK_T / TPB)  // 512 blocks
#define NTHREADS 512

// K packed to 224: k in [0,112) -> (f - oc) (valid k<100), k in [112,224) -> (f - m)
// (valid k-112<100). Dead k ranges have W1-frag == 0 and z == 0. 112 % 8 == 0 so no
// 8-element MFMA k-group straddles the boundary.
#define KHALF 112
#define NJT 7                 // j-tiles of 16 (112 >= 100)
#define NKC 7                 // k-chunks of 32 (224)
#define NBFRAG (NJT * NKC * 64)   // 3136 uint4 = 50176 B

#define NCOPY 116             // accumulator stripe: corr[112] + S at [112]
#define NSTRIPE 4             // 32 stripes thrashed L2 lines (R12: 49 MB writes)

using short8 = __attribute__((ext_vector_type(8))) short;
using f32x4  = __attribute__((ext_vector_type(4))) float;

// ---------------- ws float-offset layout ----------------
#define WS_B    0                 // 12544 floats (3136 uint4 W1-fragments, bf16 bits)
#define WS_ACC  12544             // NSTRIPE stripes x 116 floats (zeroed by k_prep_b)

__device__ __forceinline__ unsigned short f2bf(float x) {
    unsigned u = __builtin_bit_cast(unsigned, x);
    u += 0x7FFFu + ((u >> 16) & 1u);          // RNE round to bf16
    return (unsigned short)(u >> 16);
}

__device__ __forceinline__ float tanh_fast(float x) {
    float e = __expf(2.0f * x);
    return 1.0f - 2.0f / (1.0f + e);
}

// ---- Precompute W1 fragments (bf16), order [jt][kc][lane][8]; zero accumulators ----
// MFMA A operand: A[row=j][k]; per lane: j = jt*16 + (lane&15), k = kc*32 + (lane>>4)*8 + e.
__global__ __launch_bounds__(256) void k_prep_b(const float* __restrict__ W1,
                                                float* __restrict__ ws) {
    int tg = blockIdx.x * 256 + threadIdx.x;
    if (tg < NSTRIPE * NCOPY) ws[WS_ACC + tg] = 0.f;   // zero all stripes each call
    if (tg >= NBFRAG) return;
    int lane = tg & 63;
    int kc = (tg >> 6) % NKC;
    int jt = tg / (NKC * 64);
    int g = lane >> 4, r = lane & 15;
    int j = jt * 16 + r;
    unsigned short v[8];
    #pragma unroll
    for (int e = 0; e < 8; e++) {
        int kglob = kc * 32 + g * 8 + e;
        int half = (kglob >= KHALF) ? 1 : 0;
        int koff = kglob - half * KHALF;
        float x = 0.f;
        if (j < HDIM && koff < HDIM) x = W1[j * 200 + half * HDIM + koff];
        v[e] = f2bf(x);
    }
    uint4 d;
    d.x = (unsigned)v[0] | ((unsigned)v[1] << 16);
    d.y = (unsigned)v[2] | ((unsigned)v[3] << 16);
    d.z = (unsigned)v[4] | ((unsigned)v[5] << 16);
    d.w = (unsigned)v[6] | ((unsigned)v[7] << 16);
    ((uint4*)(ws + WS_B))[tg] = d;
}

__device__ __forceinline__ float4 ld4c(const float* p, bool ok) {
    float4 z = make_float4(0.f, 0.f, 0.f, 0.f);
    return ok ? *(const float4*)p : z;
}

__device__ __forceinline__ uint4 pack_diff_u(float4 a0, float4 a1,
                                             float4 b0, float4 b1) {
    union { __hip_bfloat16 h[8]; uint4 u; } u;
    u.h[0] = __float2bfloat16(a0.x - b0.x); u.h[1] = __float2bfloat16(a0.y - b0.y);
    u.h[2] = __float2bfloat16(a0.z - b0.z); u.h[3] = __float2bfloat16(a0.w - b0.w);
    u.h[4] = __float2bfloat16(a1.x - b1.x); u.h[5] = __float2bfloat16(a1.y - b1.y);
    u.h[6] = __float2bfloat16(a1.z - b1.z); u.h[7] = __float2bfloat16(a1.w - b1.w);
    return u.u;
}

// DPP row-rotate add (VALU pipe): x + rotate_within_16(x, N)
template<int CTRL>
__device__ __forceinline__ float dpp_radd(float x) {
    int y = __builtin_amdgcn_update_dpp(0, __builtin_bit_cast(int, x),
                                        CTRL, 0xF, 0xF, true);
    return x + __builtin_bit_cast(float, y);
}
__device__ __forceinline__ float row_reduce16(float x) {
    x = dpp_radd<0x121>(x);   // row_ror:1
    x = dpp_radd<0x122>(x);   // row_ror:2
    x = dpp_radd<0x124>(x);   // row_ror:4
    x = dpp_radd<0x128>(x);   // row_ror:8
    return x;                 // all 16 lanes of the row hold the row-sum
}

// PERSISTENT-LITE: 512 blocks x 4 tiles. W1/params staged ONCE per block; tile
// loop carries only sacc; pooling partials DPP-reduced per tile into WAVE-PRIVATE
// LDS slices (no barriers/atomics in loop).
// __launch_bounds__(512, 2): the backend allocates ~cap/2 VGPRs — (512,4) gave 64
// and the loop spilled (R14/R15: 300+ MB scratch). min=2 -> cap 256 -> ~128 regs,
// which still permits 4 waves/SIMD = 2 blocks/CU (the LDS limit anyway).
__global__ __launch_bounds__(NTHREADS, 2) void k_logits(
        const float* __restrict__ fe,
        const float* __restrict__ oc,
        const float* __restrict__ mvec,
        const float* __restrict__ b1,
        const float* __restrict__ W2,
        float* __restrict__ ws) {
    __shared__ __align__(16) uint4 Bs[NBFRAG];         // 50176 B (W1 table, persistent)
    __shared__ float pool2[8 * KHALF];                 // 3584 B, wave-private slices
    __shared__ float cpad[2 * KHALF];                  // oc | m, zero-padded
    __shared__ float bw[2 * KHALF];                    // b1 | W2, zero-padded
    __shared__ float sS;

    int t = threadIdx.x;
    int w = t >> 6, lane = t & 63, g = lane >> 4, r = lane & 15;

    if (t == 0) sS = 0.f;
    for (int i = t; i < 8 * KHALF; i += NTHREADS) pool2[i] = 0.f;

    // ---- stage zero-padded params to LDS (one-time, coalesced) ----
    if (t < 2 * KHALF) {
        int half = t / KHALF, k = t % KHALF;
        cpad[t] = (k < HDIM) ? (half ? mvec[k] : oc[k]) : 0.f;
        bw[t]   = (k < HDIM) ? (half ? W2[k]   : b1[k]) : 0.f;
    }

    // ---- async stage W1 table: global -> LDS, width 16, linear (ONCE per block) ----
    {
        const uint4* Bg = (const uint4*)(ws + WS_B);
        #pragma unroll
        for (int i = 0; i < 7; i++) {
            int base = i * 512 + w * 64;          // wave-uniform
            if (base < NBFRAG) {
                __builtin_amdgcn_global_load_lds(
                    (const __attribute__((address_space(1))) unsigned int*)(Bg + base + lane),
                    (__attribute__((address_space(3))) unsigned int*)(Bs + base),
                    16, 0, 0);
            }
        }
    }
    __syncthreads();   // drains vmcnt -> Bs/cpad/bw/pool2 ready

    float sacc = 0.f;

    #pragma unroll 1
    for (int tt = 0; tt < TPB; tt++) {
        int tile = blockIdx.x * TPB + tt;
        long n0 = (long)tile * FPB;
        const float* fp = fe + (n0 + w * 16 + r) * HDIM;

        // per-lane f loads (unconditional except the very last tile of the grid)
        float4 f0c[NKC], f1c[NKC];
        if (tile != NBLK_T - 1) {
            #pragma unroll
            for (int kc = 0; kc < NKC; kc++) {
                int pk = kc * 32 + g * 8;
                int col = (pk >= KHALF) ? (pk - KHALF) : pk;
                f0c[kc] = *(const float4*)(fp + col);      // may read into next row:
                f1c[kc] = *(const float4*)(fp + col + 4);  // finite; killed by W1=0
            }
        } else {
            #pragma unroll
            for (int kc = 0; kc < NKC; kc++) {
                int pk = kc * 32 + g * 8;
                int col = (pk >= KHALF) ? (pk - KHALF) : pk;
                f0c[kc] = ld4c(fp + col, col < HDIM);
                f1c[kc] = ld4c(fp + col + 4, col + 4 < HDIM);
            }
        }

        // z build from LDS-padded params (no masks)
        uint4 zabs[NKC];
        uint4 zsig[4];             // signed chunks kc=0..3 (pooling, oc-half)
        #pragma unroll
        for (int kc = 0; kc < NKC; kc++) {
            int pk = kc * 32 + g * 8;
            float4 s0 = *(const float4*)(cpad + pk);
            float4 s1 = *(const float4*)(cpad + pk + 4);
            uint4 u = pack_diff_u(f0c[kc], f1c[kc], s0, s1);
            if (kc < 4) zsig[kc] = u;
            u.x &= 0x7FFF7FFFu; u.y &= 0x7FFF7FFFu;
            u.z &= 0x7FFF7FFFu; u.w &= 0x7FFF7FFFu;
            zabs[kc] = u;
        }

        // GEMM: C[j][fact] = mfma(W1frag, |z|); C col = r = my fact; b1 in C-init
        float gacc = 0.f;
        #pragma unroll
        for (int jt = 0; jt < NJT; jt++) {
            int jb = jt * 16 + g * 4;
            float4 b1q = *(const float4*)(bw + jb);
            float4 w2q = *(const float4*)(bw + KHALF + jb);
            f32x4 acc = {b1q.x, b1q.y, b1q.z, b1q.w};
            #pragma unroll
            for (int kc = 0; kc < NKC; kc++) {
                short8 av = __builtin_bit_cast(short8, Bs[(jt * NKC + kc) * 64 + lane]);
                acc = __builtin_amdgcn_mfma_f32_16x16x32_bf16(
                    av, __builtin_bit_cast(short8, zabs[kc]), acc, 0, 0, 0);
            }
            gacc = fmaf(tanh_fast(acc[0]), w2q.x, gacc);
            gacc = fmaf(tanh_fast(acc[1]), w2q.y, gacc);
            gacc = fmaf(tanh_fast(acc[2]), w2q.z, gacc);
            gacc = fmaf(tanh_fast(acc[3]), w2q.w, gacc);
        }
        gacc += __shfl_xor(gacc, 16);
        gacc += __shfl_xor(gacc, 32);
        float w_r = __expf(gacc);   // b2 dropped (softmax-invariant); |logit| <~ 8

        sacc += w_r;                // only loop-carried register

        // pooling: p[k] = sum_r w_r*(f-oc)[r][k]; DPP-reduce; accumulate into
        // this wave's PRIVATE pool2 slice (same lane each tile -> no race).
        float p[4][8];
        #pragma unroll
        for (int c = 0; c < 4; c++) {
            union { uint4 u; unsigned short us[8]; } uz; uz.u = zsig[c];
            #pragma unroll
            for (int e = 0; e < 8; e++) {
                float zf = __builtin_bit_cast(float, ((unsigned)uz.us[e]) << 16);
                p[c][e] = w_r * zf;
            }
        }
        #pragma unroll
        for (int c = 0; c < 4; c++)
            #pragma unroll
            for (int e = 0; e < 8; e++) p[c][e] = row_reduce16(p[c][e]);

        if (r == 0) {      // lanes g=0..3 own their oc-half slots (pk<112)
            #pragma unroll
            for (int c = 0; c < 4; c++) {
                int pk = c * 32 + g * 8;
                if (pk < KHALF) {
                    float* dst = pool2 + w * KHALF + pk;
                    float4 a0 = *(float4*)(dst);
                    float4 a1 = *(float4*)(dst + 4);
                    a0.x += p[c][0]; a0.y += p[c][1]; a0.z += p[c][2]; a0.w += p[c][3];
                    a1.x += p[c][4]; a1.y += p[c][5]; a1.z += p[c][6]; a1.w += p[c][7];
                    *(float4*)(dst)     = a0;
                    *(float4*)(dst + 4) = a1;
                }
            }
        }
    }

    // ---- end-of-block: denom partial + flush ----
    float s16 = row_reduce16(sacc);   // w_r duplicated across g; take one copy
    if (lane == 0) atomicAdd(&sS, s16);
    __syncthreads();

    int cp = (blockIdx.x & (NSTRIPE - 1)) * NCOPY;
    if (t < KHALF) {
        float a = 0.f;
        #pragma unroll
        for (int w8 = 0; w8 < 8; w8++) a += pool2[w8 * KHALF + t];
        if (t < HDIM) atomicAdd(&ws[WS_ACC + cp + t], a);
    }
    if (t == 0) atomicAdd(&ws[WS_ACC + cp + KHALF], sS);
}

// Tiny epilogue: c = oc + corr/S; gated update. One block.
__global__ __launch_bounds__(128) void k_final(
        const float* __restrict__ mvec,
        const float* __restrict__ oc,
        const float* __restrict__ W3,
        const float* __restrict__ b3,
        const float* __restrict__ ws,
        float* __restrict__ out) {
    __shared__ float vv[300];
    int t = threadIdx.x;
    float S = 0.f;
    #pragma unroll
    for (int i = 0; i < NSTRIPE; i++) S += ws[WS_ACC + i * NCOPY + KHALF];
    if (t < HDIM) {
        float corr = 0.f;
        #pragma unroll
        for (int i = 0; i < NSTRIPE; i++) corr += ws[WS_ACC + i * NCOPY + t];
        vv[t] = mvec[t];
        vv[HDIM + t] = oc[t] + corr / S;
        vv[2 * HDIM + t] = oc[t];
    }
    __syncthreads();
    if (t < HDIM) {
        float a = b3[t];
        const float* wr = W3 + t * 3 * HDIM;
        #pragma unroll 4
        for (int k = 0; k < 3 * HDIM; k++) a = fmaf(wr[k], vv[k], a);
        out[t] = fmaxf(a, 0.f);
    }
}

extern "C" void kernel_launch(void* const* d_in, const int* in_sizes, int n_in,
                              void* d_out, int out_size, void* d_ws, size_t ws_size,
                              hipStream_t stream) {
    const float* mvec = (const float*)d_in[0];
    const float* oh   = (const float*)d_in[1];
    const float* fe   = (const float*)d_in[2];
    const float* W1   = (const float*)d_in[3];
    const float* b1   = (const float*)d_in[4];
    const float* W2   = (const float*)d_in[5];
    const float* W3   = (const float*)d_in[7];
    const float* b3   = (const float*)d_in[8];
    float* ws  = (float*)d_ws;
    float* out = (float*)d_out;

    k_prep_b<<<15, 256, 0, stream>>>(W1, ws);
    k_logits<<<GRID, NTHREADS, 0, stream>>>(fe, oh, mvec, b1, W2, ws);
    k_final<<<1, 128, 0, stream>>>(mvec, oh, W3, b3, ws, out);
}

// Round 17
// 77.354 us; speedup vs baseline: 5.2192x; 2.5208x over previous
//
#include <hip/hip_runtime.h>
#include <hip/hip_bf16.h>
#include <math.h>

#define HDIM 100
#define NFACT 262144
#define FPB   128             // facts per tile (8 waves x 16)
#define NBLK_T 2048           // tiles total
#define TPB   2               // tiles per block (straight-line-fenced loop)
#define GRID  (NBLK_T / TPB)  // 1024 blocks
#define NTHREADS 512

// K packed to 224: k in [0,112) -> (f - oc) (valid k<100), k in [112,224) -> (f - m)
// (valid k-112<100). Dead k ranges have W1-frag == 0 and z == 0. 112 % 8 == 0 so no
// 8-element MFMA k-group straddles the boundary.
#define KHALF 112
#define NJT 7                 // j-tiles of 16 (112 >= 100)
#define NKC 7                 // k-chunks of 32 (224)
#define NBFRAG (NJT * NKC * 64)   // 3136 uint4 = 50176 B

#define NCOPY 116             // accumulator stripe: corr[112] + S at [112]
#define NSTRIPE 4             // 32 stripes thrashed L2 lines (R12: 49 MB writes)

using short8 = __attribute__((ext_vector_type(8))) short;
using f32x4  = __attribute__((ext_vector_type(4))) float;

// ---------------- ws float-offset layout ----------------
#define WS_B    0                 // 12544 floats (3136 uint4 W1-fragments, bf16 bits)
#define WS_ACC  12544             // NSTRIPE stripes x 116 floats (zeroed by k_prep_b)

__device__ __forceinline__ unsigned short f2bf(float x) {
    unsigned u = __builtin_bit_cast(unsigned, x);
    u += 0x7FFFu + ((u >> 16) & 1u);          // RNE round to bf16
    return (unsigned short)(u >> 16);
}

__device__ __forceinline__ float tanh_fast(float x) {
    float e = __expf(2.0f * x);
    return 1.0f - 2.0f / (1.0f + e);
}

// ---- Precompute W1 fragments (bf16), order [jt][kc][lane][8]; zero accumulators ----
// MFMA A operand: A[row=j][k]; per lane: j = jt*16 + (lane&15), k = kc*32 + (lane>>4)*8 + e.
__global__ __launch_bounds__(256) void k_prep_b(const float* __restrict__ W1,
                                                float* __restrict__ ws) {
    int tg = blockIdx.x * 256 + threadIdx.x;
    if (tg < NSTRIPE * NCOPY) ws[WS_ACC + tg] = 0.f;   // zero all stripes each call
    if (tg >= NBFRAG) return;
    int lane = tg & 63;
    int kc = (tg >> 6) % NKC;
    int jt = tg / (NKC * 64);
    int g = lane >> 4, r = lane & 15;
    int j = jt * 16 + r;
    unsigned short v[8];
    #pragma unroll
    for (int e = 0; e < 8; e++) {
        int kglob = kc * 32 + g * 8 + e;
        int half = (kglob >= KHALF) ? 1 : 0;
        int koff = kglob - half * KHALF;
        float x = 0.f;
        if (j < HDIM && koff < HDIM) x = W1[j * 200 + half * HDIM + koff];
        v[e] = f2bf(x);
    }
    uint4 d;
    d.x = (unsigned)v[0] | ((unsigned)v[1] << 16);
    d.y = (unsigned)v[2] | ((unsigned)v[3] << 16);
    d.z = (unsigned)v[4] | ((unsigned)v[5] << 16);
    d.w = (unsigned)v[6] | ((unsigned)v[7] << 16);
    ((uint4*)(ws + WS_B))[tg] = d;
}

__device__ __forceinline__ float4 ld4c(const float* p, bool ok) {
    float4 z = make_float4(0.f, 0.f, 0.f, 0.f);
    return ok ? *(const float4*)p : z;
}

__device__ __forceinline__ uint4 pack_diff_u(float4 a0, float4 a1,
                                             float4 b0, float4 b1) {
    union { __hip_bfloat16 h[8]; uint4 u; } u;
    u.h[0] = __float2bfloat16(a0.x - b0.x); u.h[1] = __float2bfloat16(a0.y - b0.y);
    u.h[2] = __float2bfloat16(a0.z - b0.z); u.h[3] = __float2bfloat16(a0.w - b0.w);
    u.h[4] = __float2bfloat16(a1.x - b1.x); u.h[5] = __float2bfloat16(a1.y - b1.y);
    u.h[6] = __float2bfloat16(a1.z - b1.z); u.h[7] = __float2bfloat16(a1.w - b1.w);
    return u.u;
}

// DPP row-rotate add (VALU pipe): x + rotate_within_16(x, N)
template<int CTRL>
__device__ __forceinline__ float dpp_radd(float x) {
    int y = __builtin_amdgcn_update_dpp(0, __builtin_bit_cast(int, x),
                                        CTRL, 0xF, 0xF, true);
    return x + __builtin_bit_cast(float, y);
}
__device__ __forceinline__ float row_reduce16(float x) {
    x = dpp_radd<0x121>(x);   // row_ror:1
    x = dpp_radd<0x122>(x);   // row_ror:2
    x = dpp_radd<0x124>(x);   // row_ror:4
    x = dpp_radd<0x128>(x);   // row_ror:8
    return x;                 // all 16 lanes of the row hold the row-sum
}

// 1024 blocks x 2 tiles. W1/params staged ONCE per block. Each tile iteration is
// R13's proven straight-line body; sched_barrier(0) at iteration end prevents the
// cross-iteration software pipelining that spilled R14/R15/R16 (300+ MB scratch).
// Pooling goes to ONE 112-float LDS accumulator via ds_add_f32 (bank-safe), so
// total LDS stays ~52.4 KB -> 3 blocks/CU. min-wave=4 ((512,6)/(1024,8) spill).
__global__ __launch_bounds__(NTHREADS, 4) void k_logits(
        const float* __restrict__ fe,
        const float* __restrict__ oc,
        const float* __restrict__ mvec,
        const float* __restrict__ b1,
        const float* __restrict__ W2,
        float* __restrict__ ws) {
    __shared__ __align__(16) uint4 Bs[NBFRAG];         // 50176 B (W1 table)
    __shared__ float poolS[KHALF];                     // 448 B block accumulator
    __shared__ float cpad[2 * KHALF];                  // oc | m, zero-padded
    __shared__ float bw[2 * KHALF];                    // b1 | W2, zero-padded
    __shared__ float sS;

    int t = threadIdx.x;
    int w = t >> 6, lane = t & 63, g = lane >> 4, r = lane & 15;

    if (t == 0) sS = 0.f;
    if (t < KHALF) poolS[t] = 0.f;

    // ---- stage zero-padded params to LDS (one-time, coalesced) ----
    if (t < 2 * KHALF) {
        int half = t / KHALF, k = t % KHALF;
        cpad[t] = (k < HDIM) ? (half ? mvec[k] : oc[k]) : 0.f;
        bw[t]   = (k < HDIM) ? (half ? W2[k]   : b1[k]) : 0.f;
    }

    // ---- async stage W1 table: global -> LDS, width 16, linear (ONCE per block) ----
    {
        const uint4* Bg = (const uint4*)(ws + WS_B);
        #pragma unroll
        for (int i = 0; i < 7; i++) {
            int base = i * 512 + w * 64;          // wave-uniform
            if (base < NBFRAG) {
                __builtin_amdgcn_global_load_lds(
                    (const __attribute__((address_space(1))) unsigned int*)(Bg + base + lane),
                    (__attribute__((address_space(3))) unsigned int*)(Bs + base),
                    16, 0, 0);
            }
        }
    }
    __syncthreads();   // drains vmcnt -> Bs/cpad/bw/poolS ready

    float sacc = 0.f;

    #pragma unroll 1
    for (int tt = 0; tt < TPB; tt++) {
        int tile = blockIdx.x * TPB + tt;
        long n0 = (long)tile * FPB;
        const float* fp = fe + (n0 + w * 16 + r) * HDIM;

        // per-lane f loads (unconditional except the very last tile of the grid)
        float4 f0c[NKC], f1c[NKC];
        if (tile != NBLK_T - 1) {
            #pragma unroll
            for (int kc = 0; kc < NKC; kc++) {
                int pk = kc * 32 + g * 8;
                int col = (pk >= KHALF) ? (pk - KHALF) : pk;
                f0c[kc] = *(const float4*)(fp + col);      // may read into next row:
                f1c[kc] = *(const float4*)(fp + col + 4);  // finite; killed by W1=0
            }
        } else {
            #pragma unroll
            for (int kc = 0; kc < NKC; kc++) {
                int pk = kc * 32 + g * 8;
                int col = (pk >= KHALF) ? (pk - KHALF) : pk;
                f0c[kc] = ld4c(fp + col, col < HDIM);
                f1c[kc] = ld4c(fp + col + 4, col + 4 < HDIM);
            }
        }

        // z build from LDS-padded params (no masks)
        uint4 zabs[NKC];
        uint4 zsig[4];             // signed chunks kc=0..3 (pooling, oc-half)
        #pragma unroll
        for (int kc = 0; kc < NKC; kc++) {
            int pk = kc * 32 + g * 8;
            float4 s0 = *(const float4*)(cpad + pk);
            float4 s1 = *(const float4*)(cpad + pk + 4);
            uint4 u = pack_diff_u(f0c[kc], f1c[kc], s0, s1);
            if (kc < 4) zsig[kc] = u;
            u.x &= 0x7FFF7FFFu; u.y &= 0x7FFF7FFFu;
            u.z &= 0x7FFF7FFFu; u.w &= 0x7FFF7FFFu;
            zabs[kc] = u;
        }

        // GEMM: C[j][fact] = mfma(W1frag, |z|); C col = r = my fact; b1 in C-init
        float gacc = 0.f;
        #pragma unroll
        for (int jt = 0; jt < NJT; jt++) {
            int jb = jt * 16 + g * 4;
            float4 b1q = *(const float4*)(bw + jb);
            float4 w2q = *(const float4*)(bw + KHALF + jb);
            f32x4 acc = {b1q.x, b1q.y, b1q.z, b1q.w};
            #pragma unroll
            for (int kc = 0; kc < NKC; kc++) {
                short8 av = __builtin_bit_cast(short8, Bs[(jt * NKC + kc) * 64 + lane]);
                acc = __builtin_amdgcn_mfma_f32_16x16x32_bf16(
                    av, __builtin_bit_cast(short8, zabs[kc]), acc, 0, 0, 0);
            }
            gacc = fmaf(tanh_fast(acc[0]), w2q.x, gacc);
            gacc = fmaf(tanh_fast(acc[1]), w2q.y, gacc);
            gacc = fmaf(tanh_fast(acc[2]), w2q.z, gacc);
            gacc = fmaf(tanh_fast(acc[3]), w2q.w, gacc);
        }
        gacc += __shfl_xor(gacc, 16);
        gacc += __shfl_xor(gacc, 32);
        float w_r = __expf(gacc);   // b2 dropped (softmax-invariant); |logit| <~ 8

        sacc += w_r;                // only loop-carried register

        // pooling: p[k] = sum_r w_r*(f-oc)[r][k]; DPP-reduce; ds_add into poolS.
        float p[4][8];
        #pragma unroll
        for (int c = 0; c < 4; c++) {
            union { uint4 u; unsigned short us[8]; } uz; uz.u = zsig[c];
            #pragma unroll
            for (int e = 0; e < 8; e++) {
                float zf = __builtin_bit_cast(float, ((unsigned)uz.us[e]) << 16);
                p[c][e] = w_r * zf;
            }
        }
        #pragma unroll
        for (int c = 0; c < 4; c++)
            #pragma unroll
            for (int e = 0; e < 8; e++) p[c][e] = row_reduce16(p[c][e]);

        if (r == 0) {      // lanes g=0..3; slots pk=c*32+g*8 (+e), valid when pk<112
            #pragma unroll
            for (int c = 0; c < 4; c++) {
                int pk = c * 32 + g * 8;
                if (pk < KHALF) {
                    #pragma unroll
                    for (int e = 0; e < 8; e++)
                        atomicAdd(&poolS[pk + e], p[c][e]);
                }
            }
        }

        __builtin_amdgcn_sched_barrier(0);   // fence: no cross-tile pipelining (spill!)
    }

    // ---- end-of-block: denom partial + flush ----
    float s16 = row_reduce16(sacc);   // w_r duplicated across g; take one copy
    if (lane == 0) atomicAdd(&sS, s16);
    __syncthreads();

    int cp = (blockIdx.x & (NSTRIPE - 1)) * NCOPY;
    if (t < KHALF && t < HDIM) atomicAdd(&ws[WS_ACC + cp + t], poolS[t]);
    if (t == 0) atomicAdd(&ws[WS_ACC + cp + KHALF], sS);
}

// Tiny epilogue: c = oc + corr/S; gated update. One block.
__global__ __launch_bounds__(128) void k_final(
        const float* __restrict__ mvec,
        const float* __restrict__ oc,
        const float* __restrict__ W3,
        const float* __restrict__ b3,
        const float* __restrict__ ws,
        float* __restrict__ out) {
    __shared__ float vv[300];
    int t = threadIdx.x;
    float S = 0.f;
    #pragma unroll
    for (int i = 0; i < NSTRIPE; i++) S += ws[WS_ACC + i * NCOPY + KHALF];
    if (t < HDIM) {
        float corr = 0.f;
        #pragma unroll
        for (int i = 0; i < NSTRIPE; i++) corr += ws[WS_ACC + i * NCOPY + t];
        vv[t] = mvec[t];
        vv[HDIM + t] = oc[t] + corr / S;
        vv[2 * HDIM + t] = oc[t];
    }
    __syncthreads();
    if (t < HDIM) {
        float a = b3[t];
        const float* wr = W3 + t * 3 * HDIM;
        #pragma unroll 4
        for (int k = 0; k < 3 * HDIM; k++) a = fmaf(wr[k], vv[k], a);
        out[t] = fmaxf(a, 0.f);
    }
}

extern "C" void kernel_launch(void* const* d_in, const int* in_sizes, int n_in,
                              void* d_out, int out_size, void* d_ws, size_t ws_size,
                              hipStream_t stream) {
    const float* mvec = (const float*)d_in[0];
    const float* oh   = (const float*)d_in[1];
    const float* fe   = (const float*)d_in[2];
    const float* W1   = (const float*)d_in[3];
    const float* b1   = (const float*)d_in[4];
    const float* W2   = (const float*)d_in[5];
    const float* W3   = (const float*)d_in[7];
    const float* b3   = (const float*)d_in[8];
    float* ws  = (float*)d_ws;
    float* out = (float*)d_out;

    k_prep_b<<<15, 256, 0, stream>>>(W1, ws);
    k_logits<<<GRID, NTHREADS, 0, stream>>>(fe, oh, mvec, b1, W2, ws);
    k_final<<<1, 128, 0, stream>>>(mvec, oh, W3, b3, ws, out);
}